// Round 6
// baseline (242.169 us; speedup 1.0000x reference)
//
#include <hip/hip_runtime.h>
#include <hip/hip_bf16.h>
#include <stdint.h>

namespace {

constexpr int B = 8, T = 200, U = 50, D = 512, INNER = 640, VOCAB = 1024;
constexpr int M_TOTAL = B * T * U;          // 80000
constexpr int ROWS_E = B * T;               // 1600
constexpr int ROWS_D = B * U;               // 400
constexpr int ROWS_ED = ROWS_E + ROWS_D;    // 2000
constexpr int BM = 128, BN = 512;
constexpr int BKC = 160;                    // K-chunk; 4 chunks of 5 x K32
constexpr int CHUNK_LDS = (BM / 16) * 5 * 1024;   // 8 mi-frags x 5 ks x 1KiB = 40960 B

typedef __bf16 bf16x8 __attribute__((ext_vector_type(8)));
typedef float  f32x4  __attribute__((ext_vector_type(4)));
typedef unsigned short u16;
typedef unsigned int   u32;

__device__ __forceinline__ u16 f2bf(float f) {
  uint32_t u = __float_as_uint(f);
  uint32_t rounding = 0x7FFFu + ((u >> 16) & 1u);   // RNE
  return (u16)((u + rounding) >> 16);
}

__device__ __forceinline__ float fast_tanh(float x) {
  float e = __expf(2.0f * x);
  float r = __builtin_amdgcn_rcpf(e + 1.0f);
  return 1.0f - 2.0f * r;
}

// ---------------------------------------------------------------------------
// k_prep: merged GEMM1 (ED) + W2 fragment pack (unchanged from R5 — passed).
// ---------------------------------------------------------------------------
__global__ __launch_bounds__(320) void k_prep(const float* __restrict__ enc,
                                              const float* __restrict__ dec,
                                              const float* __restrict__ W1,
                                              const float* __restrict__ b1,
                                              const float* __restrict__ W2,
                                              float* __restrict__ ED,
                                              u16* __restrict__ W2B) {
  if (blockIdx.x >= 250) {
    // W2 pack: frag f = ks*64+nf (1 KiB); lane l: {n = nf*16+(l&15), k = ks*32+(l>>4)*8+j}
    const int idx = (blockIdx.x - 250) * 320 + threadIdx.x;   // < 81920 exact
    const int lane = idx & 63;
    const int f = idx >> 6;
    const int ks = f >> 6;
    const int nf = f & 63;
    const int n = nf * 16 + (lane & 15);
    const int k = ks * 32 + (lane >> 4) * 8;
    u16 v[8];
#pragma unroll
    for (int j = 0; j < 8; ++j)
      v[j] = f2bf(W2[(size_t)(k + j) * VOCAB + n]);
    uint64_t lo = (uint64_t)v[0] | ((uint64_t)v[1] << 16) |
                  ((uint64_t)v[2] << 32) | ((uint64_t)v[3] << 48);
    uint64_t hi = (uint64_t)v[4] | ((uint64_t)v[5] << 16) |
                  ((uint64_t)v[6] << 32) | ((uint64_t)v[7] << 48);
    uint64_t* dst = reinterpret_cast<uint64_t*>(W2B + (size_t)idx * 8);
    dst[0] = lo;
    dst[1] = hi;
    return;
  }

  __shared__ float rows[8 * D];   // 16 KiB
  const int r0 = blockIdx.x * 8;
  const bool is_enc = (r0 < ROWS_E);
  const float* src = is_enc ? (enc + (size_t)r0 * D)
                            : (dec + (size_t)(r0 - ROWS_E) * D);
  for (int i = threadIdx.x; i < 8 * D; i += 320) rows[i] = src[i];
  __syncthreads();

  const int c0 = threadIdx.x, c1 = threadIdx.x + 320;
  float acc[8][2];
  const float bias0 = is_enc ? b1[c0] : 0.f;
  const float bias1 = is_enc ? b1[c1] : 0.f;
#pragma unroll
  for (int r = 0; r < 8; ++r) { acc[r][0] = bias0; acc[r][1] = bias1; }

  for (int d = 0; d < D; d += 4) {
    float4 rv[8];
#pragma unroll
    for (int r = 0; r < 8; ++r)
      rv[r] = *reinterpret_cast<const float4*>(&rows[r * D + d]);
#pragma unroll
    for (int dd = 0; dd < 4; ++dd) {
      const float w0 = W1[(size_t)(d + dd) * INNER + c0];
      const float w1 = W1[(size_t)(d + dd) * INNER + c1];
#pragma unroll
      for (int r = 0; r < 8; ++r) {
        const float x = (dd == 0) ? rv[r].x : (dd == 1) ? rv[r].y
                        : (dd == 2) ? rv[r].z : rv[r].w;
        acc[r][0] = fmaf(x, w0, acc[r][0]);
        acc[r][1] = fmaf(x, w1, acc[r][1]);
      }
    }
  }
#pragma unroll
  for (int r = 0; r < 8; ++r) {
    ED[(size_t)(r0 + r) * INNER + c0] = acc[r][0];
    ED[(size_t)(r0 + r) * INNER + c1] = acc[r][1];
  }
}

// ---------------------------------------------------------------------------
// k_main: out[128 x 512 tile] = tanh(E1+D1) @ W2 + b2
// 512 thr = 8 waves (1x8), wave-tile 128x64, acc[8][4] = 128 regs.
// A: 160-k chunks in fragment-order LDS (2 x 40 KiB double buffer, linear
//    1 KiB frags -> zero bank conflicts). tanh(chunk c+1) overlaps MFMA(c);
//    ONE barrier per chunk. B: register double-buffer prefetch from L2.
// B traffic: 0.65 MB / 128 rows -> ~1 TB/s per XCD at MFMA pace (4x margin).
// ---------------------------------------------------------------------------
__global__ __launch_bounds__(512, 2) void k_main(const float* __restrict__ ED,
                                                 const u16* __restrict__ W2B,
                                                 const float* __restrict__ b2,
                                                 float* __restrict__ out) {
  __shared__ u16 At[2 * CHUNK_LDS / 2];   // 81920 B total (2 x 40960)
  char* At_b = reinterpret_cast<char*>(At);

  const int tid = threadIdx.x;
  const int m0 = blockIdx.x * BM;
  const int n0 = blockIdx.y * BN;

  // ---- tanh-writer mapping: row = tid>>2, j = tid&3; i=0..4 covers 160 k ----
  const int wrow = tid >> 2;
  const int wj   = tid & 3;
  {
  }
  const int m = m0 + wrow;
  const int bb = m / (T * U);
  const int rem = m - bb * (T * U);
  const int tt = rem / U;
  const int uu = rem - tt * U;
  const float* Erow = ED + (size_t)(bb * T + tt) * INNER;
  const float* Drow = ED + (size_t)(ROWS_E + bb * U + uu) * INNER;
  // LDS write base for (wrow, lhi=wj): frag (wrow>>4)*5 + i, lane = wj*16 + (wrow&15)
  const int wlds = ((wrow >> 4) * 5) * 1024 + (wj * 16 + (wrow & 15)) * 16;

#define TANH_CHUNK(cc, buf)                                                    \
  {                                                                            \
    const int kb = (cc) * BKC;                                                 \
    _Pragma("unroll")                                                          \
    for (int i = 0; i < 5; ++i) {                                              \
      const int kk = kb + (i * 4 + wj) * 8;                                    \
      const float4 e0 = *reinterpret_cast<const float4*>(Erow + kk);           \
      const float4 e1 = *reinterpret_cast<const float4*>(Erow + kk + 4);       \
      const float4 d0 = *reinterpret_cast<const float4*>(Drow + kk);           \
      const float4 d1 = *reinterpret_cast<const float4*>(Drow + kk + 4);       \
      const u32 p0 = (u32)f2bf(fast_tanh(e0.x + d0.x)) |                       \
                     ((u32)f2bf(fast_tanh(e0.y + d0.y)) << 16);                \
      const u32 p1 = (u32)f2bf(fast_tanh(e0.z + d0.z)) |                       \
                     ((u32)f2bf(fast_tanh(e0.w + d0.w)) << 16);                \
      const u32 p2 = (u32)f2bf(fast_tanh(e1.x + d1.x)) |                       \
                     ((u32)f2bf(fast_tanh(e1.y + d1.y)) << 16);                \
      const u32 p3 = (u32)f2bf(fast_tanh(e1.z + d1.z)) |                       \
                     ((u32)f2bf(fast_tanh(e1.w + d1.w)) << 16);                \
      int4 pk; pk.x = (int)p0; pk.y = (int)p1; pk.z = (int)p2; pk.w = (int)p3; \
      *reinterpret_cast<int4*>(At_b + (buf) * 40960 + wlds + i * 1024) = pk;   \
    }                                                                          \
  }

  // ---- MFMA lane mapping ----
  const int lane = tid & 63;
  const int w    = tid >> 6;     // 0..7, cols n0 + [w*64, w*64+64)
  const int llo  = lane & 15;
  const int lhi  = lane >> 4;
  const int lane16 = lane * 16;

  // B fragment base (u16 index): frag f = ksg*64 + (n0/16 + w*4 + ni)
  const u16* Bp = W2B + ((size_t)(n0 / 16 + w * 4) << 9) + lane * 8;

  f32x4 acc[8][4];
#pragma unroll
  for (int mi = 0; mi < 8; ++mi)
#pragma unroll
    for (int ni = 0; ni < 4; ++ni) acc[mi][ni] = (f32x4){0.f, 0.f, 0.f, 0.f};

  // ---- prologue: tanh chunk 0 ----
  TANH_CHUNK(0, 0)
  __syncthreads();

#pragma unroll
  for (int c = 0; c < 4; ++c) {
    const int abase = (c & 1) * 40960;

    // prefetch B for ks=0 of this chunk
    bf16x8 bcur[4];
#pragma unroll
    for (int ni = 0; ni < 4; ++ni)
      bcur[ni] = *reinterpret_cast<const bf16x8*>(Bp + (((size_t)(c * 5) * 64 + ni) << 9));

    // tanh for next chunk (overlaps this chunk's MFMAs on the VALU pipe)
    if (c < 3) TANH_CHUNK(c + 1, (c + 1) & 1)

#pragma unroll
    for (int ks = 0; ks < 5; ++ks) {
      bf16x8 bnext[4];
      if (ks < 4) {
#pragma unroll
        for (int ni = 0; ni < 4; ++ni)
          bnext[ni] = *reinterpret_cast<const bf16x8*>(
              Bp + (((size_t)(c * 5 + ks + 1) * 64 + ni) << 9));
      }
      bf16x8 a[8];
#pragma unroll
      for (int mi = 0; mi < 8; ++mi)
        a[mi] = *reinterpret_cast<const bf16x8*>(
            At_b + abase + (mi * 5 + ks) * 1024 + lane16);
#pragma unroll
      for (int mi = 0; mi < 8; ++mi)
#pragma unroll
        for (int ni = 0; ni < 4; ++ni)
          acc[mi][ni] = __builtin_amdgcn_mfma_f32_16x16x32_bf16(a[mi], bcur[ni], acc[mi][ni], 0, 0, 0);
      if (ks < 4) {
#pragma unroll
        for (int ni = 0; ni < 4; ++ni) bcur[ni] = bnext[ni];
      }
    }
    __syncthreads();   // next-chunk LDS ready; this chunk's buf reusable after next iter
  }

  // ---- epilogue ----
  float b2v[4];
#pragma unroll
  for (int ni = 0; ni < 4; ++ni) b2v[ni] = b2[n0 + w * 64 + ni * 16 + llo];

#pragma unroll
  for (int mi = 0; mi < 8; ++mi) {
#pragma unroll
    for (int q = 0; q < 4; ++q) {
      const int row = m0 + mi * 16 + lhi * 4 + q;
      float* orow = out + (size_t)row * VOCAB + n0 + w * 64 + llo;
#pragma unroll
      for (int ni = 0; ni < 4; ++ni)
        orow[ni * 16] = acc[mi][ni][q] + b2v[ni];
    }
  }
#undef TANH_CHUNK
}

}  // namespace

extern "C" void kernel_launch(void* const* d_in, const int* in_sizes, int n_in,
                              void* d_out, int out_size, void* d_ws, size_t ws_size,
                              hipStream_t stream) {
  const float* enc = (const float*)d_in[0];
  const float* dec = (const float*)d_in[1];
  const float* W1  = (const float*)d_in[2];
  const float* b1  = (const float*)d_in[3];
  const float* W2  = (const float*)d_in[4];
  const float* b2  = (const float*)d_in[5];
  float* out = (float*)d_out;

  float* ED  = (float*)d_ws;                                        // 5,120,000 B
  u16*   W2B = (u16*)((char*)d_ws + (size_t)ROWS_ED * INNER * 4);   // 1,310,720 B

  hipLaunchKernelGGL(k_prep, dim3(506), dim3(320), 0, stream,
                     enc, dec, W1, b1, W2, ED, W2B);
  hipLaunchKernelGGL(k_main, dim3(M_TOTAL / BM, VOCAB / BN), dim3(512), 0, stream,
                     ED, W2B, b2, out);
}

// Round 7
// 178.625 us; speedup vs baseline: 1.3557x; 1.3557x over previous
//
#include <hip/hip_runtime.h>
#include <hip/hip_bf16.h>
#include <stdint.h>

namespace {

constexpr int B = 8, T = 200, U = 50, D = 512, INNER = 640, VOCAB = 1024;
constexpr int M_TOTAL = B * T * U;          // 80000
constexpr int ROWS_E = B * T;               // 1600
constexpr int ROWS_D = B * U;               // 400
constexpr int ROWS_ED = ROWS_E + ROWS_D;    // 2000
constexpr int BM = 64, BN = 512;
constexpr int CK = 128;                     // K-chunk
constexpr int NCHUNK = INNER / CK;          // 5
constexpr int CHUNK_B = 16 * 1024;          // 16 frags x 1 KiB per buffer

typedef __bf16 bf16x8 __attribute__((ext_vector_type(8)));
typedef float  f32x4  __attribute__((ext_vector_type(4)));
typedef unsigned short u16;
typedef unsigned int   u32;

__device__ __forceinline__ u16 f2bf(float f) {
  uint32_t u = __float_as_uint(f);
  uint32_t rounding = 0x7FFFu + ((u >> 16) & 1u);   // RNE
  return (u16)((u + rounding) >> 16);
}

__device__ __forceinline__ float fast_tanh(float x) {
  float e = __expf(2.0f * x);
  float r = __builtin_amdgcn_rcpf(e + 1.0f);
  return 1.0f - 2.0f * r;
}

// ---------------------------------------------------------------------------
// k_prep: merged GEMM1 (ED) + W2 fragment pack.
//   blocks [0,500):   ED, 4 rows/block (more waves -> W1-load latency hidden)
//   blocks [500,756): W2B bf16 fragment pack
// ---------------------------------------------------------------------------
__global__ __launch_bounds__(320) void k_prep(const float* __restrict__ enc,
                                              const float* __restrict__ dec,
                                              const float* __restrict__ W1,
                                              const float* __restrict__ b1,
                                              const float* __restrict__ W2,
                                              float* __restrict__ ED,
                                              u16* __restrict__ W2B) {
  if (blockIdx.x >= 500) {
    // W2 pack: frag f = ks*64+nf (1 KiB); lane l: {n = nf*16+(l&15), k = ks*32+(l>>4)*8+j}
    const int idx = (blockIdx.x - 500) * 320 + threadIdx.x;   // < 81920 exact
    const int lane = idx & 63;
    const int f = idx >> 6;
    const int ks = f >> 6;
    const int nf = f & 63;
    const int n = nf * 16 + (lane & 15);
    const int k = ks * 32 + (lane >> 4) * 8;
    u16 v[8];
#pragma unroll
    for (int j = 0; j < 8; ++j)
      v[j] = f2bf(W2[(size_t)(k + j) * VOCAB + n]);
    uint64_t lo = (uint64_t)v[0] | ((uint64_t)v[1] << 16) |
                  ((uint64_t)v[2] << 32) | ((uint64_t)v[3] << 48);
    uint64_t hi = (uint64_t)v[4] | ((uint64_t)v[5] << 16) |
                  ((uint64_t)v[6] << 32) | ((uint64_t)v[7] << 48);
    uint64_t* dst = reinterpret_cast<uint64_t*>(W2B + (size_t)idx * 8);
    dst[0] = lo;
    dst[1] = hi;
    return;
  }

  __shared__ float rows[4 * D];   // 8 KiB
  const int r0 = blockIdx.x * 4;
  const bool is_enc = (r0 < ROWS_E);
  const float* src = is_enc ? (enc + (size_t)r0 * D)
                            : (dec + (size_t)(r0 - ROWS_E) * D);
  for (int i = threadIdx.x; i < 4 * D; i += 320) rows[i] = src[i];
  __syncthreads();

  const int c0 = threadIdx.x, c1 = threadIdx.x + 320;
  float acc[4][2];
  const float bias0 = is_enc ? b1[c0] : 0.f;
  const float bias1 = is_enc ? b1[c1] : 0.f;
#pragma unroll
  for (int r = 0; r < 4; ++r) { acc[r][0] = bias0; acc[r][1] = bias1; }

  for (int d = 0; d < D; d += 8) {
    f32x4 rv[4][2];
#pragma unroll
    for (int r = 0; r < 4; ++r) {
      rv[r][0] = *reinterpret_cast<const f32x4*>(&rows[r * D + d]);
      rv[r][1] = *reinterpret_cast<const f32x4*>(&rows[r * D + d + 4]);
    }
#pragma unroll
    for (int dd = 0; dd < 8; ++dd) {
      const float w0 = W1[(size_t)(d + dd) * INNER + c0];
      const float w1 = W1[(size_t)(d + dd) * INNER + c1];
#pragma unroll
      for (int r = 0; r < 4; ++r) {
        const float x = rv[r][dd >> 2][dd & 3];
        acc[r][0] = fmaf(x, w0, acc[r][0]);
        acc[r][1] = fmaf(x, w1, acc[r][1]);
      }
    }
  }
#pragma unroll
  for (int r = 0; r < 4; ++r) {
    ED[(size_t)(r0 + r) * INNER + c0] = acc[r][0];
    ED[(size_t)(r0 + r) * INNER + c1] = acc[r][1];
  }
}

// ---------------------------------------------------------------------------
// k_main: out[64 x 512 tile] = tanh(E1+D1) @ W2 + b2
// 512 thr = 8 waves, wave w owns cols [w*64,w*64+64) -> no B duplication
// within block. A: 5 K-chunks of 128, frag-order LDS double buffer
// (2 x 16 KiB = 32 KiB), ONE barrier per chunk. acc[4][4]=64 VGPR;
// __launch_bounds__(512,4) caps VGPR at 128 -> 2 blocks/CU co-resident in
// staggered phases (tanh/stores of one overlap MFMA of the other).
// ---------------------------------------------------------------------------
__global__ __launch_bounds__(512, 4) void k_main(const float* __restrict__ ED,
                                                 const u16* __restrict__ W2B,
                                                 const float* __restrict__ b2,
                                                 float* __restrict__ out) {
  __shared__ u16 At[2 * CHUNK_B / 2];   // 32768 B
  char* At_b = reinterpret_cast<char*>(At);

  const int tid = threadIdx.x;
  const int m0 = blockIdx.x * BM;
  const int n0 = blockIdx.y * BN;

  // ---- tanh-writer statics: thread covers rows {row0, row0+32}, k-group g ----
  const int row0 = tid >> 4;          // 0..31
  const int g    = tid & 15;          // 8-k group within 128-chunk
  int eoff[2], doff[2], wbyte[2];
#pragma unroll
  for (int i = 0; i < 2; ++i) {
    const int row = row0 + i * 32;
    const int m = m0 + row;
    const int b = m / (T * U);
    const int rem = m - b * (T * U);
    const int t = rem / U;
    const int u = rem - t * U;
    eoff[i] = (b * T + t) * INNER;
    doff[i] = (ROWS_E + b * U + u) * INNER;
    // frag = (row>>4)*4 + (g>>2); lane-in-frag = (g&3)*16 + (row&15)
    wbyte[i] = (((row >> 4) * 4 + (g >> 2)) << 10) + ((g & 3) * 16 + (row & 15)) * 16;
  }

  auto tanh_chunk = [&](int c, int bufsel) __attribute__((always_inline)) {
    const int kb = c * CK + g * 8;
#pragma unroll
    for (int i = 0; i < 2; ++i) {
      const float* E = ED + eoff[i] + kb;
      const float* Dp = ED + doff[i] + kb;
      const f32x4 e0 = *reinterpret_cast<const f32x4*>(E);
      const f32x4 e1 = *reinterpret_cast<const f32x4*>(E + 4);
      const f32x4 d0 = *reinterpret_cast<const f32x4*>(Dp);
      const f32x4 d1 = *reinterpret_cast<const f32x4*>(Dp + 4);
      const u32 p0 = (u32)f2bf(fast_tanh(e0[0] + d0[0])) |
                     ((u32)f2bf(fast_tanh(e0[1] + d0[1])) << 16);
      const u32 p1 = (u32)f2bf(fast_tanh(e0[2] + d0[2])) |
                     ((u32)f2bf(fast_tanh(e0[3] + d0[3])) << 16);
      const u32 p2 = (u32)f2bf(fast_tanh(e1[0] + d1[0])) |
                     ((u32)f2bf(fast_tanh(e1[1] + d1[1])) << 16);
      const u32 p3 = (u32)f2bf(fast_tanh(e1[2] + d1[2])) |
                     ((u32)f2bf(fast_tanh(e1[3] + d1[3])) << 16);
      int4 pk; pk.x = (int)p0; pk.y = (int)p1; pk.z = (int)p2; pk.w = (int)p3;
      *reinterpret_cast<int4*>(At_b + bufsel * CHUNK_B + wbyte[i]) = pk;
    }
  };

  // ---- MFMA statics ----
  const int lane = tid & 63;
  const int w    = tid >> 6;     // 0..7, cols n0 + [w*64, w*64+64)
  const int llo  = lane & 15;
  const int lhi  = lane >> 4;
  // B frag id = ksg*64 + (n0/16 + w*4 + ni); u16 off = id*512 + lane*8
  const u16* Bp = W2B + ((size_t)((n0 >> 4) + w * 4) << 9) + lane * 8;

  f32x4 acc[4][4];
#pragma unroll
  for (int mi = 0; mi < 4; ++mi)
#pragma unroll
    for (int ni = 0; ni < 4; ++ni) acc[mi][ni] = (f32x4){0.f, 0.f, 0.f, 0.f};

  // ---- pipeline: tanh(c+1) fills other buffer while MFMA consumes buf c ----
  tanh_chunk(0, 0);
  __syncthreads();

  for (int c = 0; c < NCHUNK; ++c) {
    const int ab = (c & 1) * CHUNK_B;
    if (c < NCHUNK - 1) tanh_chunk(c + 1, (c + 1) & 1);

#pragma unroll
    for (int ks = 0; ks < 4; ++ks) {
      bf16x8 bfr[4], a[4];
#pragma unroll
      for (int ni = 0; ni < 4; ++ni)
        bfr[ni] = *reinterpret_cast<const bf16x8*>(
            Bp + ((size_t)((c * 4 + ks) * 64 + ni) << 9));
#pragma unroll
      for (int mi = 0; mi < 4; ++mi)
        a[mi] = *reinterpret_cast<const bf16x8*>(
            At_b + ab + ((mi * 4 + ks) << 10) + lane * 16);
#pragma unroll
      for (int mi = 0; mi < 4; ++mi)
#pragma unroll
        for (int ni = 0; ni < 4; ++ni)
          acc[mi][ni] = __builtin_amdgcn_mfma_f32_16x16x32_bf16(a[mi], bfr[ni], acc[mi][ni], 0, 0, 0);
    }
    __syncthreads();   // chunk c reads done; chunk c+1 writes visible
  }

  // ---- epilogue (non-temporal: keep L2 for W2B/ED) ----
  float b2v[4];
#pragma unroll
  for (int ni = 0; ni < 4; ++ni) b2v[ni] = b2[n0 + w * 64 + ni * 16 + llo];

#pragma unroll
  for (int mi = 0; mi < 4; ++mi) {
#pragma unroll
    for (int q = 0; q < 4; ++q) {
      const int row = m0 + mi * 16 + lhi * 4 + q;
      float* orow = out + (size_t)row * VOCAB + n0 + w * 64 + llo;
#pragma unroll
      for (int ni = 0; ni < 4; ++ni)
        __builtin_nontemporal_store(acc[mi][ni][q] + b2v[ni], orow + ni * 16);
    }
  }
}

}  // namespace

extern "C" void kernel_launch(void* const* d_in, const int* in_sizes, int n_in,
                              void* d_out, int out_size, void* d_ws, size_t ws_size,
                              hipStream_t stream) {
  const float* enc = (const float*)d_in[0];
  const float* dec = (const float*)d_in[1];
  const float* W1  = (const float*)d_in[2];
  const float* b1  = (const float*)d_in[3];
  const float* W2  = (const float*)d_in[4];
  const float* b2  = (const float*)d_in[5];
  float* out = (float*)d_out;

  float* ED  = (float*)d_ws;                                        // 5,120,000 B
  u16*   W2B = (u16*)((char*)d_ws + (size_t)ROWS_ED * INNER * 4);   // 1,310,720 B

  hipLaunchKernelGGL(k_prep, dim3(756), dim3(320), 0, stream,
                     enc, dec, W1, b1, W2, ED, W2B);
  hipLaunchKernelGGL(k_main, dim3(M_TOTAL / BM, VOCAB / BN), dim3(512), 0, stream,
                     ED, W2B, b2, out);
}